// Round 6
// baseline (146.236 us; speedup 1.0000x reference)
//
#include <hip/hip_runtime.h>
#include <hip/hip_bf16.h>

#define T_  256
#define NN_ 2048

typedef short bf16x8 __attribute__((ext_vector_type(8)));
typedef float f32x4  __attribute__((ext_vector_type(4)));

__device__ __forceinline__ unsigned short f2bf(float x) {
    union { float f; unsigned u; } v; v.f = x;
    unsigned r = v.u + 0x7fffu + ((v.u >> 16) & 1u);   // RTNE, finite inputs
    return (unsigned short)(r >> 16);
}
__device__ __forceinline__ float bflo(unsigned w) {
    union { unsigned u; float f; } v; v.u = w << 16; return v.f;
}
__device__ __forceinline__ float bfhi(unsigned w) {
    union { unsigned u; float f; } v; v.u = w & 0xffff0000u; return v.f;
}
__device__ __forceinline__ unsigned pkbf(float lo, float hi) {
    union { __hip_bfloat16 h; unsigned short s; } a, b;
    a.h = __float2bfloat16(lo);
    b.h = __float2bfloat16(hi);
    return (unsigned)a.s | ((unsigned)b.s << 16);
}

__device__ __forceinline__ void gld_lds16(const unsigned short* g, unsigned short* l) {
    __builtin_amdgcn_global_load_lds(
        (const __attribute__((address_space(1))) unsigned int*)g,
        (__attribute__((address_space(3))) unsigned int*)l, 16, 0, 0);
}

// ---------------------------------------------------------------------------
// cs[p*512+f] = packed bf16 (cos,sin) of 2*pi*frac(p * 10000^(-f/512)).
// Token t, channel n: p = (bit9(n)? t&15 : t>>4), f = n & 511.
// ---------------------------------------------------------------------------
__global__ void build_cs(unsigned* __restrict__ cs) {
    int idx = blockIdx.x * 256 + threadIdx.x;     // 8192 entries
    int p = idx >> 9, f = idx & 511;
    float inv = powf(10000.0f, -(float)f * (1.0f / 512.0f));
    float ph  = (float)p * inv;
    float ang = (ph - floorf(ph)) * 6.28318530717958647692f;
    float s, c;
    sincosf(ang, &s, &c);
    cs[idx] = pkbf(c, s);
}

// ---------------------------------------------------------------------------
// vtrans: V fp32 (16,256,256) -> Vt bf16 [b][d][s]  (2.1 MB).
// ---------------------------------------------------------------------------
__global__ void vtrans(const float* __restrict__ V, unsigned short* __restrict__ Vt) {
    __shared__ unsigned short Tl[64 * 72];
    const int tid = threadIdx.x;
    const int b  = blockIdx.x >> 4;
    const int s0 = ((blockIdx.x >> 2) & 3) << 6;
    const int d0 = (blockIdx.x & 3) << 6;
    const float* Vb = V + (size_t)b * 65536;
#pragma unroll
    for (int u = 0; u < 4; u++) {
        int lin = u * 256 + tid;
        int srow = lin >> 4, c4 = (lin & 15) << 2;
        float4 v = *(const float4*)(Vb + (size_t)(s0 + srow) * 256 + d0 + c4);
        Tl[(c4 + 0) * 72 + srow] = f2bf(v.x);
        Tl[(c4 + 1) * 72 + srow] = f2bf(v.y);
        Tl[(c4 + 2) * 72 + srow] = f2bf(v.z);
        Tl[(c4 + 3) * 72 + srow] = f2bf(v.w);
    }
    __syncthreads();
    unsigned short* Vtb = Vt + (size_t)b * 65536;
#pragma unroll
    for (int u = 0; u < 2; u++) {
        int lin = u * 256 + tid;
        int drow = lin >> 3, sc8 = (lin & 7) << 3;
        *(uint4*)(Vtb + (size_t)(d0 + drow) * 256 + s0 + sc8) =
            *(const uint4*)(&Tl[drow * 72 + sc8]);
    }
}

// ===========================================================================
// SPLIT PATH (needs ~144 MiB workspace)
// ===========================================================================

// ---------------------------------------------------------------------------
// rope_cast: Q,K fp32 -> Qr,Kr bf16 with RoPE; 1/sqrt(N) folded into Qr.
// Streaming, 8-oct (64-element) units per thread.  Memory-bound.
// ---------------------------------------------------------------------------
__launch_bounds__(256)
__global__ void rope_cast(const float* __restrict__ Q, const float* __restrict__ K,
                          const unsigned* __restrict__ cs,
                          unsigned short* __restrict__ Qr, unsigned short* __restrict__ Kr) {
    const size_t base = (size_t)blockIdx.x * 256 + threadIdx.x;   // < 1048576
#pragma unroll
    for (int j = 0; j < 8; j++) {
        size_t o = base + (size_t)j * 1048576;
        const float* src;
        unsigned short* dst;
        float sc;
        if (j < 4) { src = Q; dst = Qr; sc = 0.02209708691207961f; }
        else       { src = K; dst = Kr; sc = 1.0f; o -= 4194304; }
        const int t = (int)((o >> 8) & 255);
        const int w = (int)((o >> 6) & 1);
        const int f = ((int)o & 63) << 3;
        const int p = w ? (t & 15) : (t >> 4);
        const float* qp = src + o * 8;
        float4 q0 = *(const float4*)(qp);
        float4 q1 = *(const float4*)(qp + 4);
        const unsigned* cp = cs + (p << 9) + f;
        uint4 u0 = *(const uint4*)(cp);
        uint4 u1 = *(const uint4*)(cp + 4);
        q0.x *= sc; q0.y *= sc; q0.z *= sc; q0.w *= sc;
        q1.x *= sc; q1.y *= sc; q1.z *= sc; q1.w *= sc;
        uint4 out;
        out.x = pkbf(q0.x*bflo(u0.x) - q0.y*bfhi(u0.x),
                     q0.y*bflo(u0.y) + q0.x*bfhi(u0.y));
        out.y = pkbf(q0.z*bflo(u0.z) - q0.w*bfhi(u0.z),
                     q0.w*bflo(u0.w) + q0.z*bfhi(u0.w));
        out.z = pkbf(q1.x*bflo(u1.x) - q1.y*bfhi(u1.x),
                     q1.y*bflo(u1.y) + q1.x*bfhi(u1.y));
        out.w = pkbf(q1.z*bflo(u1.z) - q1.w*bfhi(u1.z),
                     q1.w*bflo(u1.w) + q1.z*bfhi(u1.w));
        *(uint4*)(dst + o * 8) = out;
    }
}

// ---------------------------------------------------------------------------
// gemm1b: scores = Qr . Kr^T  (pure bf16 GEMM, m97 recipe).
// 128x64 tile, BK=64, 256 threads (4 waves), 512 blocks = 2 blocks/CU.
// global_load_lds dwordx4 staging with pre-swizzled global source (T2/G21);
// swizzled conflict-free ds_read_b128 fragment reads.
// ---------------------------------------------------------------------------
__launch_bounds__(256)
__global__ void gemm1b(const unsigned short* __restrict__ Qr,
                       const unsigned short* __restrict__ Kr,
                       unsigned short* __restrict__ scores) {
    __shared__ __align__(16) unsigned short A[128 * 64];
    __shared__ __align__(16) unsigned short Bt[64 * 64];

    const int tid  = threadIdx.x;
    const int bh   = blockIdx.x & 63;          // bh%8 per XCD
    const int tile = blockIdx.x >> 6;          // 0..7
    const int ti = (tile >> 2) << 7;           // 0,128
    const int si = (tile & 3) << 6;            // 0..192

    const unsigned short* Qb = Qr + (size_t)bh * (T_ * NN_);
    const unsigned short* Kb = Kr + (size_t)bh * (T_ * NN_);

    // staging: A 4 units, B 2 units per thread; src column pre-swizzled
    const unsigned short* srcA[4]; unsigned short* dstA[4];
    const unsigned short* srcB[2]; unsigned short* dstB[2];
#pragma unroll
    for (int u = 0; u < 4; u++) {
        int lin = u * 256 + tid;
        int row = lin >> 3, cu = lin & 7;
        int scol = cu ^ (row & 7);             // inverse-swizzled source
        srcA[u] = Qb + (size_t)(ti + row) * NN_ + scol * 8;
        dstA[u] = &A[lin * 8];
    }
#pragma unroll
    for (int u = 0; u < 2; u++) {
        int lin = u * 256 + tid;
        int row = lin >> 3, cu = lin & 7;
        int scol = cu ^ (row & 7);
        srcB[u] = Kb + (size_t)(si + row) * NN_ + scol * 8;
        dstB[u] = &Bt[lin * 8];
    }

    const int wv = tid >> 6, lane = tid & 63;
    const int lr = lane & 15, lg = lane >> 4;
    const int m0 = (wv >> 1) * 64;
    const int n0 = (wv & 1) * 32;

    f32x4 acc[4][2];
#pragma unroll
    for (int i = 0; i < 4; i++)
#pragma unroll
        for (int j = 0; j < 2; j++) acc[i][j] = (f32x4){0.f, 0.f, 0.f, 0.f};

    for (int k0 = 0; k0 < NN_; k0 += 64) {
#pragma unroll
        for (int u = 0; u < 4; u++) gld_lds16(srcA[u] + k0, dstA[u]);
#pragma unroll
        for (int u = 0; u < 2; u++) gld_lds16(srcB[u] + k0, dstB[u]);
        __syncthreads();

#pragma unroll
        for (int kk = 0; kk < 64; kk += 32) {
            bf16x8 af[4], bfr[2];
#pragma unroll
            for (int mi = 0; mi < 4; mi++) {
                int row = m0 + mi * 16 + lr;
                int c   = (kk >> 3) + lg;
                af[mi] = *(const bf16x8*)(&A[row * 64 + ((c ^ (row & 7)) << 3)]);
            }
#pragma unroll
            for (int ni = 0; ni < 2; ni++) {
                int row = n0 + ni * 16 + lr;
                int c   = (kk >> 3) + lg;
                bfr[ni] = *(const bf16x8*)(&Bt[row * 64 + ((c ^ (row & 7)) << 3)]);
            }
#pragma unroll
            for (int mi = 0; mi < 4; mi++)
#pragma unroll
                for (int ni = 0; ni < 2; ni++)
                    acc[mi][ni] = __builtin_amdgcn_mfma_f32_16x16x32_bf16(
                        af[mi], bfr[ni], acc[mi][ni], 0, 0, 0);
        }
        __syncthreads();
    }

    // epilogue (1/sqrt(N) already folded into Qr)
    unsigned short* sb = scores + (size_t)bh * (T_ * T_);
#pragma unroll
    for (int mi = 0; mi < 4; mi++) {
        int tr = ti + m0 + mi * 16 + lg * 4;
#pragma unroll
        for (int ni = 0; ni < 2; ni++) {
            int sc = si + n0 + ni * 16 + lr;
#pragma unroll
            for (int r = 0; r < 4; r++)
                sb[(size_t)(tr + r) * 256 + sc] = f2bf(acc[mi][ni][r]);
        }
    }
}

// ---------------------------------------------------------------------------
// gemm2b: out = scores @ V via Vt bf16 [d][s].  Same glds skeleton, K=256.
// ---------------------------------------------------------------------------
__launch_bounds__(256)
__global__ void gemm2b(const unsigned short* __restrict__ scores,
                       const unsigned short* __restrict__ Vt, float* __restrict__ out) {
    __shared__ __align__(16) unsigned short A[128 * 64];
    __shared__ __align__(16) unsigned short Bt[64 * 64];

    const int tid  = threadIdx.x;
    const int bh   = blockIdx.x & 63;
    const int b    = bh >> 2;
    const int tile = blockIdx.x >> 6;          // 0..7
    const int ti = (tile >> 2) << 7;           // 0,128   (t rows)
    const int d0 = (tile & 3) << 6;            // 0..192  (d cols)

    const unsigned short* Sb  = scores + (size_t)bh * 65536;
    const unsigned short* Vtb = Vt + (size_t)b * 65536;

    const unsigned short* srcA[4]; unsigned short* dstA[4];
    const unsigned short* srcB[2]; unsigned short* dstB[2];
#pragma unroll
    for (int u = 0; u < 4; u++) {
        int lin = u * 256 + tid;
        int row = lin >> 3, cu = lin & 7;
        int scol = cu ^ (row & 7);
        srcA[u] = Sb + (size_t)(ti + row) * 256 + scol * 8;
        dstA[u] = &A[lin * 8];
    }
#pragma unroll
    for (int u = 0; u < 2; u++) {
        int lin = u * 256 + tid;
        int row = lin >> 3, cu = lin & 7;
        int scol = cu ^ (row & 7);
        srcB[u] = Vtb + (size_t)(d0 + row) * 256 + scol * 8;
        dstB[u] = &Bt[lin * 8];
    }

    const int wv = tid >> 6, lane = tid & 63;
    const int lr = lane & 15, lg = lane >> 4;
    const int m0 = (wv >> 1) * 64;
    const int n0 = (wv & 1) * 32;

    f32x4 acc[4][2];
#pragma unroll
    for (int i = 0; i < 4; i++)
#pragma unroll
        for (int j = 0; j < 2; j++) acc[i][j] = (f32x4){0.f, 0.f, 0.f, 0.f};

    for (int k0 = 0; k0 < 256; k0 += 64) {
#pragma unroll
        for (int u = 0; u < 4; u++) gld_lds16(srcA[u] + k0, dstA[u]);
#pragma unroll
        for (int u = 0; u < 2; u++) gld_lds16(srcB[u] + k0, dstB[u]);
        __syncthreads();

#pragma unroll
        for (int kk = 0; kk < 64; kk += 32) {
            bf16x8 af[4], bfr[2];
#pragma unroll
            for (int mi = 0; mi < 4; mi++) {
                int row = m0 + mi * 16 + lr;
                int c   = (kk >> 3) + lg;
                af[mi] = *(const bf16x8*)(&A[row * 64 + ((c ^ (row & 7)) << 3)]);
            }
#pragma unroll
            for (int ni = 0; ni < 2; ni++) {
                int row = n0 + ni * 16 + lr;
                int c   = (kk >> 3) + lg;
                bfr[ni] = *(const bf16x8*)(&Bt[row * 64 + ((c ^ (row & 7)) << 3)]);
            }
#pragma unroll
            for (int mi = 0; mi < 4; mi++)
#pragma unroll
                for (int ni = 0; ni < 2; ni++)
                    acc[mi][ni] = __builtin_amdgcn_mfma_f32_16x16x32_bf16(
                        af[mi], bfr[ni], acc[mi][ni], 0, 0, 0);
        }
        __syncthreads();
    }

    float* ob = out + (size_t)bh * 65536;
#pragma unroll
    for (int mi = 0; mi < 4; mi++) {
        int tr = ti + m0 + mi * 16 + lg * 4;
#pragma unroll
        for (int ni = 0; ni < 2; ni++) {
            int dc = d0 + n0 + ni * 16 + lr;
#pragma unroll
            for (int r = 0; r < 4; r++)
                ob[(size_t)(tr + r) * 256 + dc] = acc[mi][ni][r];
        }
    }
}

// ===========================================================================
// FALLBACK PATH (R5 fused kernels, used when workspace is too small)
// ===========================================================================
struct QKSet { float4 a[4]; float4 b[2]; };

__launch_bounds__(512, 4)
__global__ void gemm1(const float* __restrict__ Q, const float* __restrict__ K,
                      const unsigned* __restrict__ cs, unsigned short* __restrict__ scores) {
    __shared__ __align__(16) unsigned short Als[2][128 * 72];
    __shared__ __align__(16) unsigned short Bls[2][64 * 72];
    __shared__ __align__(16) unsigned csl[2][1024];

    const int tid  = threadIdx.x;
    const int bh   = blockIdx.x & 63;
    const int tile = blockIdx.x >> 6;
    const int ti = (tile >> 2) << 7;
    const int si = (tile & 3) << 6;

    const float* Qb = Q + (size_t)bh * (T_ * NN_);
    const float* Kb = K + (size_t)bh * (T_ * NN_);

    const float* qpA[2]; int phA[2], pwA[2], c8A[2], ldsA[2];
    const float* qpB0;   int phB, pwB, c8B, ldsB0;
#pragma unroll
    for (int u = 0; u < 2; u++) {
        int lin = u * 512 + tid;
        int row = lin >> 3, c8 = (lin & 7) << 3;
        int gr = ti + row;
        qpA[u] = Qb + (size_t)gr * NN_ + c8;
        phA[u] = gr >> 4;  pwA[u] = gr & 15;
        c8A[u] = c8;       ldsA[u] = row * 72 + c8;
    }
    {
        int row = tid >> 3, c8 = (tid & 7) << 3;
        int gr = si + row;
        qpB0 = Kb + (size_t)gr * NN_ + c8;
        phB = gr >> 4;  pwB = gr & 15;
        c8B = c8;       ldsB0 = row * 72 + c8;
    }

    const int csE = tid * 2;
    const int csP = csE >> 6, csC = csE & 63;

    const int wv = tid >> 6, lane = tid & 63;
    const int lr = lane & 15, lg = lane >> 4;
    const int m0 = (wv >> 1) << 5;
    const int n0 = (wv & 1) << 5;

    f32x4 acc[2][2];
#pragma unroll
    for (int i = 0; i < 2; i++)
#pragma unroll
        for (int j = 0; j < 2; j++) acc[i][j] = (f32x4){0.f, 0.f, 0.f, 0.f};

    auto LOAD = [&](QKSet& s, int slab) {
        const int k0 = slab << 6;
#pragma unroll
        for (int u = 0; u < 2; u++) {
            s.a[2*u]   = *(const float4*)(qpA[u] + k0);
            s.a[2*u+1] = *(const float4*)(qpA[u] + k0 + 4);
        }
        s.b[0] = *(const float4*)(qpB0 + k0);
        s.b[1] = *(const float4*)(qpB0 + k0 + 4);
    };
    auto CSLOADG = [&](uint2& cr, int slab) {
        const int fk = (slab << 6) & 511;
        cr = *(const uint2*)(cs + (csP << 9) + fk + csC);
    };
    auto CSWRITE = [&](int par, const uint2& cr) {
        *(uint2*)(&csl[par][csE]) = cr;
    };
    auto CSSTD = [&](int par, int slab) {
        const int fk = (slab << 6) & 511;
        *(uint2*)(&csl[par][csE]) = *(const uint2*)(cs + (csP << 9) + fk + csC);
    };
    auto ROT = [&](const float4& f0, const float4& f1,
                   const uint4& u0, const uint4& u1) -> uint4 {
        uint4 o;
        o.x = pkbf(f0.x*bflo(u0.x) - f0.y*bfhi(u0.x),
                   f0.y*bflo(u0.y) + f0.x*bfhi(u0.y));
        o.y = pkbf(f0.z*bflo(u0.z) - f0.w*bfhi(u0.z),
                   f0.w*bflo(u0.w) + f0.z*bfhi(u0.w));
        o.z = pkbf(f1.x*bflo(u1.x) - f1.y*bfhi(u1.x),
                   f1.y*bflo(u1.y) + f1.x*bfhi(u1.y));
        o.w = pkbf(f1.z*bflo(u1.z) - f1.w*bfhi(u1.z),
                   f1.w*bflo(u1.w) + f1.z*bfhi(u1.w));
        return o;
    };
    auto WRITE = [&](int buf, int par, const QKSet& s, int slab) {
        const int w = (slab >> 3) & 1;
#pragma unroll
        for (int u = 0; u < 2; u++) {
            const unsigned* cp = &csl[par][((w ? pwA[u] : phA[u]) << 6) + c8A[u]];
            uint4 u0 = *(const uint4*)cp, u1 = *(const uint4*)(cp + 4);
            *(uint4*)(&Als[buf][ldsA[u]]) = ROT(s.a[2*u], s.a[2*u+1], u0, u1);
        }
        const unsigned* cp = &csl[par][((w ? pwB : phB) << 6) + c8B];
        uint4 u0 = *(const uint4*)cp, u1 = *(const uint4*)(cp + 4);
        *(uint4*)(&Bls[buf][ldsB0]) = ROT(s.b[0], s.b[1], u0, u1);
    };
    auto COMPUTE = [&](int buf) {
        __builtin_amdgcn_s_setprio(1);
#pragma unroll
        for (int kk = 0; kk < 64; kk += 32) {
            bf16x8 af[2], bfr[2];
#pragma unroll
            for (int mi = 0; mi < 2; mi++)
                af[mi] = *(const bf16x8*)(&Als[buf][(m0 + mi * 16 + lr) * 72 + kk + lg * 8]);
#pragma unroll
            for (int ni = 0; ni < 2; ni++)
                bfr[ni] = *(const bf16x8*)(&Bls[buf][(n0 + ni * 16 + lr) * 72 + kk + lg * 8]);
#pragma unroll
            for (int mi = 0; mi < 2; mi++)
#pragma unroll
                for (int ni = 0; ni < 2; ni++)
                    acc[mi][ni] = __builtin_amdgcn_mfma_f32_16x16x32_bf16(
                        af[mi], bfr[ni], acc[mi][ni], 0, 0, 0);
        }
        __builtin_amdgcn_s_setprio(0);
    };
    auto BAR = [&]() {
        asm volatile("s_waitcnt lgkmcnt(0)" ::: "memory");
        __builtin_amdgcn_s_barrier();
        asm volatile("" ::: "memory");
    };

    QKSet s0, s1; uint2 cr0, cr1;
    LOAD(s0, 0);
    LOAD(s1, 1);
    CSSTD(0, 0);
    CSSTD(1, 1);
    CSLOADG(cr0, 2);
    CSLOADG(cr1, 3);
    __builtin_amdgcn_sched_barrier(0);
    BAR();
    WRITE(0, 0, s0, 0);
    LOAD(s0, 2);
    __builtin_amdgcn_sched_barrier(0);
    BAR();

#pragma unroll 1
    for (int t2 = 0; t2 < 15; t2++) {
        const int t = t2 * 2;
        COMPUTE(0);
        WRITE(1, 1, s1, t + 1);
        CSWRITE(0, cr0);
        {
            int s3 = t + 3; if (s3 > 31) s3 = 31;
            int s4 = t + 4; if (s4 > 31) s4 = 31;
            LOAD(s1, s3);
            CSLOADG(cr0, s4);
        }
        __builtin_amdgcn_sched_barrier(0);
        BAR();
        COMPUTE(1);
        WRITE(0, 0, s0, t + 2);
        CSWRITE(1, cr1);
        {
            int s4 = t + 4; if (s4 > 31) s4 = 31;
            int s5 = t + 5; if (s5 > 31) s5 = 31;
            LOAD(s0, s4);
            CSLOADG(cr1, s5);
        }
        __builtin_amdgcn_sched_barrier(0);
        BAR();
    }
    COMPUTE(0);
    WRITE(1, 1, s1, 31);
    BAR();
    COMPUTE(1);

    const float rs = 0.02209708691207961f;
    unsigned short* sb = scores + (size_t)bh * (T_ * T_);
#pragma unroll
    for (int mi = 0; mi < 2; mi++) {
        int tr = ti + m0 + mi * 16 + lg * 4;
#pragma unroll
        for (int ni = 0; ni < 2; ni++) {
            int sc = si + n0 + ni * 16 + lr;
#pragma unroll
            for (int r = 0; r < 4; r++)
                sb[(size_t)(tr + r) * 256 + sc] = f2bf(acc[mi][ni][r] * rs);
        }
    }
}

__launch_bounds__(256, 2)
__global__ void gemm2(const unsigned short* __restrict__ scores,
                      const unsigned short* __restrict__ Vt, float* __restrict__ out) {
    __shared__ __align__(16) unsigned short Als[2][128 * 72];
    __shared__ __align__(16) unsigned short Bls[2][64 * 72];

    const int tid  = threadIdx.x;
    const int bh   = blockIdx.x & 63;
    const int b    = bh >> 2;
    const int tile = blockIdx.x >> 6;
    const int ti = (tile >> 2) << 7;
    const int d0 = (tile & 3) << 6;

    const unsigned short* Sb  = scores + (size_t)bh * 65536;
    const unsigned short* Vtb = Vt + (size_t)b * 65536;

    const int wv = tid >> 6, lane = tid & 63;
    const int lr = lane & 15, lg = lane >> 4;
    const int m0 = (wv >> 1) * 64;
    const int n0 = (wv & 1) * 32;

    f32x4 acc[4][2];
#pragma unroll
    for (int i = 0; i < 4; i++)
#pragma unroll
        for (int j = 0; j < 2; j++) acc[i][j] = (f32x4){0.f, 0.f, 0.f, 0.f};

    uint4 sA[4], sB[2];

    auto LOAD = [&](int k0) {
#pragma unroll
        for (int u = 0; u < 4; u++) {
            int lin = u * 256 + tid;
            int row = lin >> 3, c8 = (lin & 7) << 3;
            sA[u] = *(const uint4*)(Sb + (size_t)(ti + row) * 256 + k0 + c8);
        }
#pragma unroll
        for (int u = 0; u < 2; u++) {
            int lin = u * 256 + tid;
            int row = lin >> 3, c8 = (lin & 7) << 3;
            sB[u] = *(const uint4*)(Vtb + (size_t)(d0 + row) * 256 + k0 + c8);
        }
    };
    auto WRITE = [&](int buf) {
#pragma unroll
        for (int u = 0; u < 4; u++) {
            int lin = u * 256 + tid;
            int row = lin >> 3, c8 = (lin & 7) << 3;
            *(uint4*)(&Als[buf][row * 72 + c8]) = sA[u];
        }
#pragma unroll
        for (int u = 0; u < 2; u++) {
            int lin = u * 256 + tid;
            int row = lin >> 3, c8 = (lin & 7) << 3;
            *(uint4*)(&Bls[buf][row * 72 + c8]) = sB[u];
        }
    };
    auto COMPUTE = [&](int buf) {
        __builtin_amdgcn_s_setprio(1);
#pragma unroll
        for (int kk = 0; kk < 64; kk += 32) {
            bf16x8 af[4], bfr[2];
#pragma unroll
            for (int mi = 0; mi < 4; mi++)
                af[mi] = *(const bf16x8*)(&Als[buf][(m0 + mi * 16 + lr) * 72 + kk + lg * 8]);
#pragma unroll
            for (int ni = 0; ni < 2; ni++)
                bfr[ni] = *(const bf16x8*)(&Bls[buf][(n0 + ni * 16 + lr) * 72 + kk + lg * 8]);
#pragma unroll
            for (int mi = 0; mi < 4; mi++)
#pragma unroll
                for (int ni = 0; ni < 2; ni++)
                    acc[mi][ni] = __builtin_amdgcn_mfma_f32_16x16x32_bf16(
                        af[mi], bfr[ni], acc[mi][ni], 0, 0, 0);
        }
        __builtin_amdgcn_s_setprio(0);
    };
    auto BAR = [&]() {
        asm volatile("s_waitcnt lgkmcnt(0)" ::: "memory");
        __builtin_amdgcn_s_barrier();
        asm volatile("" ::: "memory");
    };

    LOAD(0);
    WRITE(0);
    BAR();

    int cur = 0;
#pragma unroll 1
    for (int t = 0; t < 3; t++) {
        LOAD((t + 1) * 64);
        COMPUTE(cur);
        WRITE(cur ^ 1);
        __builtin_amdgcn_sched_barrier(0);
        BAR();
        cur ^= 1;
    }
    COMPUTE(cur);

    float* ob = out + (size_t)bh * 65536;
#pragma unroll
    for (int mi = 0; mi < 4; mi++) {
        int tr = ti + m0 + mi * 16 + lg * 4;
#pragma unroll
        for (int ni = 0; ni < 2; ni++) {
            int dc = d0 + n0 + ni * 16 + lr;
#pragma unroll
            for (int r = 0; r < 4; r++)
                ob[(size_t)(tr + r) * 256 + dc] = acc[mi][ni][r];
        }
    }
}

// ---------------------------------------------------------------------------
extern "C" void kernel_launch(void* const* d_in, const int* in_sizes, int n_in,
                              void* d_out, int out_size, void* d_ws, size_t ws_size,
                              hipStream_t stream) {
    const float* Q = (const float*)d_in[0];
    const float* K = (const float*)d_in[1];
    const float* V = (const float*)d_in[2];
    float* out = (float*)d_out;

    unsigned* cs = (unsigned*)d_ws;                                        // 32 KB
    unsigned short* scores = (unsigned short*)((char*)d_ws + 32768);       // 8 MB
    unsigned short* Vt = (unsigned short*)((char*)d_ws + 32768 + 8388608); // 2 MB
    unsigned short* Qr = (unsigned short*)((char*)d_ws + 16777216);        // 64 MB
    unsigned short* Kr = (unsigned short*)((char*)d_ws + 83886080);        // 64 MB

    build_cs<<<dim3(32), dim3(256), 0, stream>>>(cs);
    vtrans<<<dim3(256), dim3(256), 0, stream>>>(V, Vt);

    if (ws_size >= 150994944ULL) {
        rope_cast<<<dim3(4096), dim3(256), 0, stream>>>(Q, K, cs, Qr, Kr);
        gemm1b<<<dim3(512), dim3(256), 0, stream>>>(Qr, Kr, scores);
        gemm2b<<<dim3(512), dim3(256), 0, stream>>>(scores, Vt, out);
    } else {
        gemm1<<<dim3(512), dim3(512), 0, stream>>>(Q, K, cs, scores);
        gemm2<<<dim3(512), dim3(256), 0, stream>>>(scores, Vt, out);
    }
}